// Round 7
// baseline (311.246 us; speedup 1.0000x reference)
//
#include <hip/hip_runtime.h>
#include <hip/hip_bf16.h>

#define SEQ 1024
#define DIM 128
#define NEG_SLOPE 0.1f

typedef __bf16 bf16x8 __attribute__((ext_vector_type(8)));
typedef float f32x4v __attribute__((ext_vector_type(4)));
typedef unsigned char uchar;

// d_ws layout (bytes):
//   [0, 4M)    ntq fp8 [b][d][o]
//   [4M, +32K) Wt bf16 [d][k]
//   [.., +32K) Bt bf16 [d][k]
//   [4M+64K, +32M) maskq fp8 [b][i][o]  (0x38 = 1.0, 0x00 = 0)
#define NTQ_BYTES ((size_t)32 * 128 * 1024)

__device__ __forceinline__ unsigned short bfb(float f) {
    __bf16 h = (__bf16)f;
    return __builtin_bit_cast(unsigned short, h);
}

__device__ __forceinline__ uchar f32_to_e4m3(float f) {
#if __has_builtin(__builtin_amdgcn_cvt_pk_fp8_f32)
    int r = __builtin_amdgcn_cvt_pk_fp8_f32(f, f, 0, false);
    return (uchar)(r & 0xff);
#else
    unsigned u = __builtin_bit_cast(unsigned, f);
    unsigned s = (u >> 24) & 0x80;
    int e = (u >> 23) & 0xff;
    unsigned m = u & 0x7fffff;
    int te = e - 120;
    if (te >= 1) {
        unsigned keep = m >> 20, rest = m & 0xfffff;
        keep += (rest > 0x80000u) || (rest == 0x80000u && (keep & 1));
        if (keep == 8) { keep = 0; ++te; }
        if (te > 15) return (uchar)(s | 0x7e);
        return (uchar)(s | (te << 3) | keep);
    }
    float af = f < 0 ? -f : f;
    int q = (int)(af * 512.0f + 0.5f);
    if (q > 7) q = 7;
    return (uchar)(s | q);
#endif
}

__device__ __forceinline__ long mk64(unsigned lo, unsigned hi) {
    return (long)(((unsigned long long)hi << 32) | lo);
}

// ---- K1: adj[b][o][i] -> maskq[b][i][o] fp8. PURE SEQUENTIAL reads,
// full-128B-line writes. Block = (batch, 128-row o-chunk), 1024 threads,
// thread t owns column i = t: reads one int per row (lane-consecutive =
// 256 B/instr coalesced), writes its 128 o-bytes as 8 x uint4. No LDS.
__global__ __launch_bounds__(1024, 1)
void quant_adj(const int* __restrict__ adj, uchar* __restrict__ mq)
{
    const int b  = blockIdx.x >> 3;
    const int oc = blockIdx.x & 7;
    const int t  = threadIdx.x;   // = i
    const int* __restrict__ src = adj + ((size_t)b * SEQ + oc * 128) * SEQ + t;
    uchar* dst = mq + ((size_t)b * SEQ + t) * SEQ + oc * 128;

    #pragma unroll
    for (int p = 0; p < 8; ++p) {
        unsigned w[4];
        #pragma unroll
        for (int g = 0; g < 4; ++g) {
            unsigned v = 0;
            #pragma unroll
            for (int j = 0; j < 4; ++j) {
                const int x = src[(size_t)(p * 16 + g * 4 + j) * SEQ];
                v |= (x != 0 ? 0x38u : 0u) << (8 * j);
            }
            w[g] = v;
        }
        uint4 o4; o4.x = w[0]; o4.y = w[1]; o4.z = w[2]; o4.w = w[3];
        *(uint4*)(dst + p * 16) = o4;
    }
}

// ---- K2: nodes[b][o][d] f32 -> ntq[b][d][o] fp8 ----
__global__ __launch_bounds__(256)
void transpose_nodes(const float* __restrict__ nodes, uchar* __restrict__ nq)
{
    __shared__ float lds[64][33];
    const int b  = blockIdx.x >> 6;
    const int ot = (blockIdx.x >> 2) & 15;
    const int dt = blockIdx.x & 3;
    const int o0 = ot << 6, d0 = dt << 5;
    const int t  = threadIdx.x;

    const float* src = nodes + ((size_t)(b * SEQ + o0)) * DIM + d0;
    #pragma unroll
    for (int p = 0; p < 8; ++p) {
        const int o = (t >> 5) + p * 8;
        const int d = t & 31;
        lds[o][d] = src[(size_t)o * DIM + d];
    }
    __syncthreads();

    const int d_loc = t >> 3;
    const int p0    = (t & 7) * 8;
    union { uchar b[8]; uint2 u; } pk;
    #pragma unroll
    for (int j = 0; j < 8; ++j) pk.b[j] = f32_to_e4m3(lds[p0 + j][d_loc]);
    *(uint2*)(nq + ((size_t)(b * DIM + d0 + d_loc)) * SEQ + o0 + p0) = pk.u;
}

// ---- K3: W,B [k][d] f32 -> Wt,Bt [d][k] bf16 ----
__global__ __launch_bounds__(256)
void transpose_wb(const float* __restrict__ W, const float* __restrict__ Bm,
                  unsigned short* __restrict__ wt, unsigned short* __restrict__ bt)
{
    const int which = blockIdx.x & 1;
    const int slice = blockIdx.x >> 1;
    const float* in = which ? Bm : W;
    unsigned short* out = which ? bt : wt;
    const int base = slice * 1024;
    #pragma unroll
    for (int r = 0; r < 4; ++r) {
        const int idx = base + r * 256 + threadIdx.x;
        const int d = idx >> 7, k = idx & 127;
        out[idx] = bfb(in[k * DIM + d]);
    }
}

// ---- K4 main: barrier-free fp8 K-loop, A & B both 16B-contiguous global
// reads (maskq rows / ntq rows), depth-2 prefetch; bf16 epilogue.
// tile 32(i) x 128(d), grid 1024 = 4 blocks/CU.
__global__ __launch_bounds__(256, 4)
void gcn_main(const float* __restrict__ nodes,
              const uchar* __restrict__ mq,
              const uchar* __restrict__ nq,
              const unsigned short* __restrict__ wt,
              const unsigned short* __restrict__ bt,
              float* __restrict__ out)
{
    __shared__ unsigned short pooled[32][136];

    const int bid   = blockIdx.x;
    const int xcd   = bid & 7;
    const int slot  = bid >> 3;
    const int batch = ((slot >> 5) << 3) | xcd;   // batch's 32 blocks share an XCD (ntq L2 reuse)
    const int itile = slot & 31;
    const int i0    = itile << 5;

    const int tid  = threadIdx.x;
    const int wave = tid >> 6;
    const int lane = tid & 63;
    const int wh   = wave >> 1;   // i-half (16 rows)
    const int wn   = wave & 1;    // d-half (64 cols)
    const int lrow = lane & 15;
    const int quad = lane >> 4;

    const uchar* __restrict__ mq_b    = mq + (size_t)batch * SEQ * SEQ;
    const uchar* __restrict__ nq_b    = nq + (size_t)batch * DIM * SEQ;
    const float* __restrict__ nodes_b = nodes + (size_t)batch * SEQ * DIM;

    f32x4v acc[4] = {};
    f32x4v acc_cnt = {};
    const long ones = 0x3838383838383838L;   // 8x e4m3 1.0

    // A row: mask[i = i0+wh*16+lrow][o]; B rows: nodes_t[d = wn*64+lrow+nf*16][o]
    const uchar* pa0 = mq_b + (size_t)(i0 + wh * 16 + lrow) * SEQ + quad * 16;
    const uchar* pb0 = nq_b + (size_t)(wn * 64 + lrow) * SEQ + quad * 16;

    uint4 Ab[3], Bb[3][4];
    #pragma unroll
    for (int k = 0; k < 2; ++k) {
        Ab[k] = *(const uint4*)(pa0 + k * 64);
        #pragma unroll
        for (int nf = 0; nf < 4; ++nf)
            Bb[k][nf] = *(const uint4*)(pb0 + (size_t)nf * 16 * SEQ + k * 64);
    }

    #pragma unroll
    for (int n = 0; n < 16; ++n) {
        if (n < 14) {
            const int s = (n + 2) % 3;
            Ab[s] = *(const uint4*)(pa0 + (n + 2) * 64);
            #pragma unroll
            for (int nf = 0; nf < 4; ++nf)
                Bb[s][nf] = *(const uint4*)(pb0 + (size_t)nf * 16 * SEQ + (n + 2) * 64);
        }
        const uint4 a4 = Ab[n % 3];
        #pragma unroll
        for (int half = 0; half < 2; ++half) {
            const long a64 = half ? mk64(a4.z, a4.w) : mk64(a4.x, a4.y);
            #pragma unroll
            for (int nf = 0; nf < 4; ++nf) {
                const uint4 b4 = Bb[n % 3][nf];
                const long b64 = half ? mk64(b4.z, b4.w) : mk64(b4.x, b4.y);
                acc[nf] = __builtin_amdgcn_mfma_f32_16x16x32_fp8_fp8(a64, b64, acc[nf], 0, 0, 0);
            }
            acc_cnt = __builtin_amdgcn_mfma_f32_16x16x32_fp8_fp8(a64, ones, acc_cnt, 0, 0, 0);
        }
    }

    // poolsum -> pooled (divide by exact MFMA in-degree), C-layout -> A-layout via LDS
    #pragma unroll
    for (int r = 0; r < 4; ++r) {
        const int row = wh * 16 + quad * 4 + r;
        const float cnt = acc_cnt[r];
        const float inv = (cnt > 0.5f) ? 1.0f / cnt : 0.0f;
        #pragma unroll
        for (int nf = 0; nf < 4; ++nf) {
            const int col = wn * 64 + nf * 16 + lrow;
            pooled[row][col] = bfb(acc[nf][r] * inv);
        }
    }
    __syncthreads();

    f32x4v acc2[4] = {};
    const int d_b0 = wn * 64 + lrow;

    // pooled @ W + nodes @ B  (K=128, bf16)
    #pragma unroll
    for (int ks = 0; ks < 4; ++ks) {
        const int k0 = ks * 32 + quad * 8;
        bf16x8 av, av2, bw[4], bb[4];
        av = *(const bf16x8*)&pooled[wh * 16 + lrow][k0];
        {
            const float* p = nodes_b + (size_t)(i0 + wh * 16 + lrow) * DIM + k0;
            const float4 f1 = *(const float4*)p;
            const float4 f2 = *(const float4*)(p + 4);
            av2[0] = (__bf16)f1.x; av2[1] = (__bf16)f1.y;
            av2[2] = (__bf16)f1.z; av2[3] = (__bf16)f1.w;
            av2[4] = (__bf16)f2.x; av2[5] = (__bf16)f2.y;
            av2[6] = (__bf16)f2.z; av2[7] = (__bf16)f2.w;
        }
        #pragma unroll
        for (int nf = 0; nf < 4; ++nf) {
            bw[nf] = *(const bf16x8*)(wt + (size_t)(d_b0 + nf * 16) * DIM + k0);
            bb[nf] = *(const bf16x8*)(bt + (size_t)(d_b0 + nf * 16) * DIM + k0);
        }
        #pragma unroll
        for (int nf = 0; nf < 4; ++nf) {
            acc2[nf] = __builtin_amdgcn_mfma_f32_16x16x32_bf16(av,  bw[nf], acc2[nf], 0, 0, 0);
            acc2[nf] = __builtin_amdgcn_mfma_f32_16x16x32_bf16(av2, bb[nf], acc2[nf], 0, 0, 0);
        }
    }

    // leaky-relu + store
    float* out_b = out + (size_t)batch * SEQ * DIM;
    #pragma unroll
    for (int nf = 0; nf < 4; ++nf) {
        const int col = wn * 64 + nf * 16 + lrow;
        #pragma unroll
        for (int r = 0; r < 4; ++r) {
            const int row = i0 + wh * 16 + quad * 4 + r;
            const float x = acc2[nf][r];
            out_b[(size_t)row * DIM + col] = (x > 0.0f) ? x : NEG_SLOPE * x;
        }
    }
}

extern "C" void kernel_launch(void* const* d_in, const int* in_sizes, int n_in,
                              void* d_out, int out_size, void* d_ws, size_t ws_size,
                              hipStream_t stream) {
    const float* nodes = (const float*)d_in[0];
    const int*   adj   = (const int*)d_in[1];
    const float* W     = (const float*)d_in[2];
    const float* Bm    = (const float*)d_in[3];
    float*       out   = (float*)d_out;

    uchar* nq = (uchar*)d_ws;
    unsigned short* wt = (unsigned short*)(nq + NTQ_BYTES);
    unsigned short* bt = wt + 16384;
    uchar* mq = (uchar*)(bt + 16384);

    quant_adj      <<<dim3(256),  dim3(1024), 0, stream>>>(adj, mq);
    transpose_nodes<<<dim3(2048), dim3(256),  0, stream>>>(nodes, nq);
    transpose_wb   <<<dim3(32),   dim3(256),  0, stream>>>(W, Bm, wt, bt);
    gcn_main       <<<dim3(1024), dim3(256),  0, stream>>>(nodes, mq, nq, wt, bt, out);
}